// Round 4
// baseline (232.843 us; speedup 1.0000x reference)
//
#include <hip/hip_runtime.h>

constexpr int BATCH = 131072;
constexpr int T = 10;
constexpr int H = 32;
constexpr int JB = 8;   // accumulator-chain block: 8 independent chains pinned

// ws layout (floats): [0 .. 33*32) = 33 rows x 32:
//   rows 0..31: W_hh^T  (row k = column k of W_hh)
//   row  32   : W_ih    (x is treated as the 33rd hidden element)
// [33*32 .. 33*32+32) = b_ih + b_hh
__global__ void __launch_bounds__(1024)
rnn_setup(const float* __restrict__ W_ih, const float* __restrict__ W_hh,
          const float* __restrict__ b_ih, const float* __restrict__ b_hh,
          float* __restrict__ ws) {
    const int i = threadIdx.x;            // 0..1023
    const int j = i >> 5, k = i & 31;
    ws[k * H + j] = W_hh[i];              // transpose
    if (i < H) {
        ws[H * H + i]  = W_ih[i];         // row 32
        ws[33 * H + i] = b_ih[i] + b_hh[i];
    }
}

__global__ void __launch_bounds__(256, 2)
rnn_main(const float* __restrict__ x,      // [B, T]
         const float* __restrict__ h0,     // [B, H]
         const float* __restrict__ w,      // ws: 33x32 wT rows + bias
         const float* __restrict__ W_out,  // [H]
         const float* __restrict__ b_out,  // [1]
         float* __restrict__ out)          // outs [B*T] then hT [B*H]
{
    const int b = blockIdx.x * 256 + threadIdx.x;
    const float* __restrict__ bs = w + 33 * H;

    float h[H];
    {
        const float4* hp = reinterpret_cast<const float4*>(h0 + (size_t)b * H);
        #pragma unroll
        for (int i = 0; i < H / 4; ++i) {
            float4 v = hp[i];
            h[4*i+0] = v.x; h[4*i+1] = v.y; h[4*i+2] = v.z; h[4*i+3] = v.w;
        }
    }

    const float* xb = x + (size_t)b * T;
    float*       ob = out + (size_t)b * T;

    float xt = xb[0];

    #pragma unroll 1
    for (int t = 0; t < T; ++t) {
        float xnext = (t + 1 < T) ? xb[t + 1] : 0.0f;

        float hn[H];
        float o = b_out[0];

        // j blocked by 8: per pass, 8 independent FMA chains, k-inner.
        // asm volatile pins the interleave (scheduler cannot re-serialize
        // it to shrink register pressure, which is what sank R2).
        #pragma unroll
        for (int jb = 0; jb < H; jb += JB) {
            float a[JB];
            #pragma unroll
            for (int j = 0; j < JB; ++j) a[j] = bs[jb + j];

            #pragma unroll
            for (int k = 0; k <= H; ++k) {        // 33 rows; row 32 pairs with xt
                const float hk = (k < H) ? h[k] : xt;
                const float* __restrict__ wr = w + k * H + jb;
                #pragma unroll
                for (int j = 0; j < JB; ++j) {
                    // v_fmac_f32 dst += src0*src1 ; SGPR weight in src0 (legal),
                    // h in vsrc1. Loads stay unpinned -> compiler prefetches rows.
                    asm volatile("v_fmac_f32 %0, %1, %2"
                                 : "+v"(a[j])
                                 : "s"(wr[j]), "v"(hk));
                }
            }

            #pragma unroll
            for (int j = 0; j < JB; ++j) {
                // tanh(v) = 1 - 2/(exp(2v)+1); overflow-safe at both ends
                float e  = __expf(2.0f * a[j]);
                float hv = 1.0f - 2.0f * __builtin_amdgcn_rcpf(e + 1.0f);
                hn[jb + j] = hv;
                o = fmaf(hv, W_out[jb + j], o);
            }
        }

        #pragma unroll
        for (int j = 0; j < H; ++j) h[j] = hn[j];

        ob[t] = o;
        xt = xnext;
    }

    float4* hout = reinterpret_cast<float4*>(out + (size_t)BATCH * T + (size_t)b * H);
    #pragma unroll
    for (int i = 0; i < H / 4; ++i) {
        float4 v;
        v.x = h[4*i+0]; v.y = h[4*i+1]; v.z = h[4*i+2]; v.w = h[4*i+3];
        hout[i] = v;
    }
}

extern "C" void kernel_launch(void* const* d_in, const int* in_sizes, int n_in,
                              void* d_out, int out_size, void* d_ws, size_t ws_size,
                              hipStream_t stream) {
    const float* x     = (const float*)d_in[0];
    const float* h0    = (const float*)d_in[1];
    const float* W_ih  = (const float*)d_in[2];
    const float* W_hh  = (const float*)d_in[3];
    const float* b_ih  = (const float*)d_in[4];
    const float* b_hh  = (const float*)d_in[5];
    const float* W_out = (const float*)d_in[6];
    const float* b_out = (const float*)d_in[7];
    float* out = (float*)d_out;
    float* ws  = (float*)d_ws;

    rnn_setup<<<1, 1024, 0, stream>>>(W_ih, W_hh, b_ih, b_hh, ws);
    rnn_main<<<BATCH / 256, 256, 0, stream>>>(
        x, h0, ws, W_out, b_out, out);
}

// Round 5
// 33.179 us; speedup vs baseline: 7.0178x; 7.0178x over previous
//
#include <hip/hip_runtime.h>

typedef __attribute__((ext_vector_type(4))) float f32x4;
typedef __attribute__((ext_vector_type(8))) short s16x8;
typedef __attribute__((ext_vector_type(4))) int   i32x4;

constexpr int BATCH = 131072;
constexpr int T = 10;
constexpr int H = 32;
constexpr int LS = 17;   // LDS row stride (16 m + 1 pad) in dwords

__device__ __forceinline__ unsigned cvt_pk_bf16(float a, float b) {
    unsigned d;
    asm("v_cvt_pk_bf16_f32 %0, %1, %2" : "=v"(d) : "v"(a), "v"(b));
    return d;   // lo16 = bf16(a), hi16 = bf16(b)
}

// 8 consecutive-k f32 values -> bf16x8 hi fragment + bf16x8 lo fragment
__device__ __forceinline__ void pack_hilo(const float (&v)[8], i32x4& hi, i32x4& lo) {
    #pragma unroll
    for (int p = 0; p < 4; ++p) {
        unsigned hbits = cvt_pk_bf16(v[2*p], v[2*p+1]);
        float f0h = __builtin_bit_cast(float, hbits << 16);
        float f1h = __builtin_bit_cast(float, hbits & 0xFFFF0000u);
        hi[p] = (int)hbits;
        lo[p] = (int)cvt_pk_bf16(v[2*p] - f0h, v[2*p+1] - f1h);
    }
}

__device__ __forceinline__ f32x4 mfma16(i32x4 a, i32x4 b, f32x4 c) {
    return __builtin_amdgcn_mfma_f32_16x16x32_bf16(
        __builtin_bit_cast(s16x8, a), __builtin_bit_cast(s16x8, b), c, 0, 0, 0);
}

__device__ __forceinline__ float fast_tanh(float v) {
    float e = __expf(2.0f * v);
    return 1.0f - 2.0f * __builtin_amdgcn_rcpf(e + 1.0f);
}

extern "C" __global__ void __launch_bounds__(256)
rnn_mfma(const float* __restrict__ x,      // [B, T]
         const float* __restrict__ h0,     // [B, H]
         const float* __restrict__ W_ih,   // [H]
         const float* __restrict__ W_hh,   // [H, H] row-major
         const float* __restrict__ b_ih,   // [H]
         const float* __restrict__ b_hh,   // [H]
         const float* __restrict__ W_out,  // [H]
         const float* __restrict__ b_out,  // [1]
         float* __restrict__ out)          // outs [B*T] then hT [B*H]
{
    __shared__ float lds[4][H * LS];       // per-wave f32 tile [k=32][m=16+pad]

    const int tid  = threadIdx.x;
    const int wave = tid >> 6;
    const int lane = tid & 63;
    const int nl   = lane & 15;            // D col n / A row m
    const int g    = lane >> 4;            // 16-lane group
    const int b0   = blockIdx.x * 64 + wave * 16;

    float* sh = lds[wave];

    // ---- B fragments for W_hh (constant across steps) ----
    // B[k][n] = W_hh[n][k]: lane holds n = nl (+16 tile1), k = 8g..8g+7
    i32x4 bhi0, blo0, bhi1, blo1;
    {
        float v[8];
        const float4* p = reinterpret_cast<const float4*>(W_hh + nl * H + 8 * g);
        float4 a = p[0], b = p[1];
        v[0]=a.x; v[1]=a.y; v[2]=a.z; v[3]=a.w; v[4]=b.x; v[5]=b.y; v[6]=b.z; v[7]=b.w;
        pack_hilo(v, bhi0, blo0);
        const float4* q = reinterpret_cast<const float4*>(W_hh + (nl + 16) * H + 8 * g);
        float4 c = q[0], d = q[1];
        v[0]=c.x; v[1]=c.y; v[2]=c.z; v[3]=c.w; v[4]=d.x; v[5]=d.y; v[6]=d.z; v[7]=d.w;
        pack_hilo(v, bhi1, blo1);
    }

    // ---- B fragment for W_out: only column n'=0 nonzero ----
    i32x4 bouth = {0,0,0,0}, boutl = {0,0,0,0};
    {
        float v[8];
        const float4* p = reinterpret_cast<const float4*>(W_out + 8 * g);
        float4 a = p[0], b = p[1];
        v[0]=a.x; v[1]=a.y; v[2]=a.z; v[3]=a.w; v[4]=b.x; v[5]=b.y; v[6]=b.z; v[7]=b.w;
        i32x4 th, tl;
        pack_hilo(v, th, tl);
        if (nl == 0) { bouth = th; boutl = tl; }
    }

    const float wih0 = W_ih[nl],       wih1 = W_ih[nl + 16];
    const float bs0  = b_ih[nl]      + b_hh[nl];
    const float bs1  = b_ih[nl + 16] + b_hh[nl + 16];
    const float bo   = b_out[0];

    // ---- initial A fragments from h0: lane m = nl, k = 8g..8g+7 ----
    i32x4 ahi, alo;
    {
        float v[8];
        const float4* p = reinterpret_cast<const float4*>(h0 + (size_t)(b0 + nl) * H + 8 * g);
        float4 a = p[0], b = p[1];
        v[0]=a.x; v[1]=a.y; v[2]=a.z; v[3]=a.w; v[4]=b.x; v[5]=b.y; v[6]=b.z; v[7]=b.w;
        pack_hilo(v, ahi, alo);
    }

    // x for rows m = 4g+r
    float xc[4];
    #pragma unroll
    for (int r = 0; r < 4; ++r) xc[r] = x[(size_t)(b0 + 4 * g + r) * T];

    float hnew[8];   // current h (f32), D layout: tile0 r=0..3, tile1 r=4..7

    #pragma unroll 1
    for (int t = 0; t < T; ++t) {
        // ---- o[t-1] = h_t · W_out (A frag already transposed) ----
        if (t > 0) {
            f32x4 oacc = {0.f, 0.f, 0.f, 0.f};
            oacc = mfma16(ahi, bouth, oacc);
            oacc = mfma16(alo, bouth, oacc);
            oacc = mfma16(ahi, boutl, oacc);
            if (nl == 0) {
                #pragma unroll
                for (int r = 0; r < 4; ++r)
                    out[(size_t)(b0 + 4 * g + r) * T + (t - 1)] = oacc[r] + bo;
            }
        }

        // ---- C init: bias + x*W_ih (pure fp32, x never rounded) ----
        f32x4 d0, d1;
        #pragma unroll
        for (int r = 0; r < 4; ++r) { d0[r] = fmaf(xc[r], wih0, bs0);
                                      d1[r] = fmaf(xc[r], wih1, bs1); }

        // prefetch next x
        if (t + 1 < T) {
            #pragma unroll
            for (int r = 0; r < 4; ++r) xc[r] = x[(size_t)(b0 + 4 * g + r) * T + t + 1];
        }

        // ---- h_t · W_hh^T : split-bf16, 3 products x 2 N-tiles ----
        d0 = mfma16(ahi, bhi0, d0);
        d1 = mfma16(ahi, bhi1, d1);
        d0 = mfma16(alo, bhi0, d0);
        d1 = mfma16(alo, bhi1, d1);
        d0 = mfma16(ahi, blo0, d0);
        d1 = mfma16(ahi, blo1, d1);

        // ---- tanh ----
        #pragma unroll
        for (int r = 0; r < 4; ++r) { hnew[r]     = fast_tanh(d0[r]);
                                      hnew[4 + r] = fast_tanh(d1[r]); }

        // ---- D -> A transpose via wave-private LDS (f32) ----
        // write: lane holds rows m=4g..4g+3 of cols n=nl, nl+16 -> [k=n][m]
        {
            float* w0 = sh + nl * LS + 4 * g;
            w0[0] = hnew[0]; w0[1] = hnew[1]; w0[2] = hnew[2]; w0[3] = hnew[3];
            float* w1 = sh + (nl + 16) * LS + 4 * g;
            w1[0] = hnew[4]; w1[1] = hnew[5]; w1[2] = hnew[6]; w1[3] = hnew[7];
        }
        // read: lane m = nl, k = 8g..8g+7 (stride LS, <=2-way bank alias = free)
        {
            float v[8];
            const float* rp = sh + 8 * g * LS + nl;
            #pragma unroll
            for (int r = 0; r < 8; ++r) v[r] = rp[r * LS];
            pack_hilo(v, ahi, alo);
        }
    }

    // ---- o[T-1] from final A (= h_T) ----
    {
        f32x4 oacc = {0.f, 0.f, 0.f, 0.f};
        oacc = mfma16(ahi, bouth, oacc);
        oacc = mfma16(alo, bouth, oacc);
        oacc = mfma16(ahi, boutl, oacc);
        if (nl == 0) {
            #pragma unroll
            for (int r = 0; r < 4; ++r)
                out[(size_t)(b0 + 4 * g + r) * T + (T - 1)] = oacc[r] + bo;
        }
    }

    // ---- hT (f32, from last hnew): rows m=4g+r, cols nl / nl+16 ----
    float* hb = out + (size_t)BATCH * T;
    #pragma unroll
    for (int r = 0; r < 4; ++r) {
        hb[(size_t)(b0 + 4 * g + r) * H + nl]      = hnew[r];
        hb[(size_t)(b0 + 4 * g + r) * H + nl + 16] = hnew[4 + r];
    }
}

extern "C" void kernel_launch(void* const* d_in, const int* in_sizes, int n_in,
                              void* d_out, int out_size, void* d_ws, size_t ws_size,
                              hipStream_t stream) {
    const float* x     = (const float*)d_in[0];
    const float* h0    = (const float*)d_in[1];
    const float* W_ih  = (const float*)d_in[2];
    const float* W_hh  = (const float*)d_in[3];
    const float* b_ih  = (const float*)d_in[4];
    const float* b_hh  = (const float*)d_in[5];
    const float* W_out = (const float*)d_in[6];
    const float* b_out = (const float*)d_in[7];
    float* out = (float*)d_out;

    rnn_mfma<<<BATCH / 64, 256, 0, stream>>>(
        x, h0, W_ih, W_hh, b_ih, b_hh, W_out, b_out, out);
}